// Round 1
// baseline (42.349 us; speedup 1.0000x reference)
//
#include <hip/hip_runtime.h>

// DepthLossForImgBEV: weighted BCE over (B,N,D,H,W) depth logits vs one-hot
// bucketized GT depth, reduced to a scalar mean * 3.0.
//
// B=2 N=6 D=112 H=64 W=176.  depth: (B, N*D, H, W) f32; depth_gt: (B,N,H,W) f32.
// Memory-bound: 60.6 MB depth read + 0.54 MB gt (L2-cached, read 112x).

namespace {

constexpr int B_ = 2, N_ = 6, D_ = 112, H_ = 64, W_ = 176;
constexpr int HW_ = H_ * W_;                                  // 11264 (div by 4)
constexpr long long TOT_ = (long long)B_ * N_ * D_ * HW_;     // 15,138,816
constexpr int NQ_ = (int)(TOT_ / 4);                          // 3,784,704 float4s
constexpr float SCALE_ = (float)(3.0 / (double)TOT_);         // LOSS_DEPTH_WEIGHT / numel

// One element's weighted BCE term.
//   softplus(x)  = relu(x)  + log1p(exp(-|x|))
//   softplus(-x) = relu(-x) + log1p(exp(-|x|))
// bce = min(softplus(-x),100) if d==idx else min(softplus(x),100); times weight.
__device__ __forceinline__ float bce_term(float g, float x, int d) {
    float w = (g != 0.0f) ? 1.0f : 0.0f;            // lidar-valid weight
    int idx = (int)floorf((g - 2.0f) * 2.0f);       // (g - DBOUND0) / DBOUND2
    idx = idx < 0 ? 0 : (idx > D_ ? D_ : idx);      // clip to [0, D]; idx==D -> no target row
    float ax = fabsf(x);
    float c = __logf(1.0f + __expf(-ax));           // shared log1p(exp(-|x|)) term
    float r = (d == idx) ? fmaxf(-x, 0.0f) : fmaxf(x, 0.0f);
    return w * fminf(c + r, 100.0f);                // BCE per-log-term clamp at -100
}

__global__ __launch_bounds__(256) void depth_loss_kernel(
        const float* __restrict__ gt, const float* __restrict__ dp,
        float* __restrict__ out) {
    float s = 0.0f;
    const int stride = gridDim.x * blockDim.x;
    for (int q = blockIdx.x * blockDim.x + threadIdx.x; q < NQ_; q += stride) {
        int e = q << 2;               // flat element index into depth (B,N,D,H,W)
        int hw = e % HW_;             // position within image plane (quad-aligned)
        int sl = e / HW_;             // (b*N + n)*D + d
        int d  = sl % D_;
        int bn = sl / D_;
        float4 g = *reinterpret_cast<const float4*>(gt + bn * HW_ + hw);
        float4 x = *reinterpret_cast<const float4*>(dp + e);
        s += bce_term(g.x, x.x, d);
        s += bce_term(g.y, x.y, d);
        s += bce_term(g.z, x.z, d);
        s += bce_term(g.w, x.w, d);
    }
    // wave64 butterfly reduce
    #pragma unroll
    for (int off = 32; off > 0; off >>= 1) s += __shfl_down(s, off, 64);
    __shared__ float lsum[4];
    const int wid = threadIdx.x >> 6;
    if ((threadIdx.x & 63) == 0) lsum[wid] = s;
    __syncthreads();
    if (threadIdx.x == 0) {
        float t = (lsum[0] + lsum[1]) + (lsum[2] + lsum[3]);
        atomicAdd(out, t * SCALE_);
    }
}

}  // namespace

extern "C" void kernel_launch(void* const* d_in, const int* in_sizes, int n_in,
                              void* d_out, int out_size, void* d_ws, size_t ws_size,
                              hipStream_t stream) {
    const float* gt = (const float*)d_in[0];   // depth_gt (B,N,H,W)
    const float* dp = (const float*)d_in[1];   // depth (B,N*D,H,W)
    float* out = (float*)d_out;
    // Harness poisons d_out (0xAA) and never re-poisons between replays: zero it
    // on-stream every launch (memset node is graph-capture legal).
    hipMemsetAsync(out, 0, sizeof(float), stream);
    // Memory-bound: cap grid at 2048 blocks, grid-stride the rest (G11).
    depth_loss_kernel<<<2048, 256, 0, stream>>>(gt, dp, out);
}

// Round 2
// 21.977 us; speedup vs baseline: 1.9270x; 1.9270x over previous
//
#include <hip/hip_runtime.h>

// DepthLossForImgBEV: weighted BCE over (B,N,D,H,W) depth logits vs one-hot
// bucketized GT depth, reduced to a scalar mean * 3.0.
//
// B=2 N=6 D=112 H=64 W=176.  depth: (B,N*D,H,W) f32 (60.6 MB); depth_gt:
// (B,N,H,W) f32 (0.54 MB, L2-resident). Memory-bound; roofline ~10 us.
//
// Structure: no memset, no atomics (a per-replay 4B hipMemsetAsync node cost
// ~39 us of fixed overhead in R0). Kernel1 overwrites one partial/block in
// d_ws; kernel2 overwrites d_out[0]. Each thread owns one (bn, hw-quad,
// 7-deep d-chunk) column: gt quad + bucket idx hoisted out of the d loop.

namespace {

constexpr int B_ = 2, N_ = 6, D_ = 112, H_ = 64, W_ = 176;
constexpr int HW_   = H_ * W_;          // 11264
constexpr int NHWQ_ = HW_ / 4;          // 2816 float4 quads per image plane
constexpr int NCH_  = 16, DPC_ = 7;     // 16 d-chunks x 7 slices = 112
constexpr int NBN_  = B_ * N_;          // 12
constexpr long long TOT_ = (long long)NBN_ * D_ * HW_;   // 15,138,816
constexpr int NTHR_ = NBN_ * NCH_ * NHWQ_;               // 540,672
constexpr int NBLK_ = NTHR_ / 256;                       // 2112 blocks
constexpr float SCALE_ = (float)(3.0 / (double)TOT_);    // 3.0 / numel

// bce = min(softplus(+-x), 100) * w;  softplus(x) = relu(x) + log1p(exp(-|x|))
__device__ __forceinline__ float term(float x, float w, bool hit) {
    float c = __logf(1.0f + __expf(-fabsf(x)));          // shared log term
    float r = hit ? fmaxf(-x, 0.0f) : fmaxf(x, 0.0f);
    return w * fminf(c + r, 100.0f);
}

__device__ __forceinline__ int bucket(float g) {
    int i = (int)floorf((g - 2.0f) * 2.0f);   // (g - DBOUND0) / DBOUND2
    return i < 0 ? 0 : (i > D_ ? D_ : i);     // clip [0,D]; D never matches d
}

__global__ __launch_bounds__(256) void depth_loss_part(
        const float* __restrict__ gt, const float* __restrict__ dp,
        float* __restrict__ part) {
    const int t    = blockIdx.x * 256 + threadIdx.x;
    const int hwq  = t % NHWQ_;           // quad within image plane
    const int rest = t / NHWQ_;
    const int ch   = rest % NCH_;         // which 7-slice d-chunk
    const int bn   = rest / NCH_;         // (b*N + n)
    const int hw   = hwq * 4;
    const int d0   = ch * DPC_;

    // per-column: weight + bucket index, computed once for 7 d-slices
    const float4 g = *reinterpret_cast<const float4*>(gt + bn * HW_ + hw);
    const float w0 = (g.x != 0.0f) ? 1.0f : 0.0f;
    const float w1 = (g.y != 0.0f) ? 1.0f : 0.0f;
    const float w2 = (g.z != 0.0f) ? 1.0f : 0.0f;
    const float w3 = (g.w != 0.0f) ? 1.0f : 0.0f;
    const int  i0 = bucket(g.x), i1 = bucket(g.y), i2 = bucket(g.z), i3 = bucket(g.w);

    const float* p = dp + ((long long)bn * D_ + d0) * HW_ + hw;
    float s = 0.0f;
    #pragma unroll
    for (int i = 0; i < DPC_; ++i) {
        const int d = d0 + i;
        float4 x = *reinterpret_cast<const float4*>(p);
        p += HW_;
        s += term(x.x, w0, d == i0);
        s += term(x.y, w1, d == i1);
        s += term(x.z, w2, d == i2);
        s += term(x.w, w3, d == i3);
    }

    // block reduce -> one partial per block (overwrite, no init needed)
    #pragma unroll
    for (int off = 32; off > 0; off >>= 1) s += __shfl_down(s, off, 64);
    __shared__ float ls[4];
    if ((threadIdx.x & 63) == 0) ls[threadIdx.x >> 6] = s;
    __syncthreads();
    if (threadIdx.x == 0)
        part[blockIdx.x] = (ls[0] + ls[1]) + (ls[2] + ls[3]);
}

__global__ __launch_bounds__(256) void depth_loss_final(
        const float* __restrict__ part, float* __restrict__ out) {
    float s = 0.0f;
    for (int i = threadIdx.x; i < NBLK_; i += 256) s += part[i];
    #pragma unroll
    for (int off = 32; off > 0; off >>= 1) s += __shfl_down(s, off, 64);
    __shared__ float ls[4];
    if ((threadIdx.x & 63) == 0) ls[threadIdx.x >> 6] = s;
    __syncthreads();
    if (threadIdx.x == 0)
        out[0] = ((ls[0] + ls[1]) + (ls[2] + ls[3])) * SCALE_;
}

}  // namespace

extern "C" void kernel_launch(void* const* d_in, const int* in_sizes, int n_in,
                              void* d_out, int out_size, void* d_ws, size_t ws_size,
                              hipStream_t stream) {
    const float* gt = (const float*)d_in[0];   // depth_gt (B,N,H,W)
    const float* dp = (const float*)d_in[1];   // depth (B,N*D,H,W)
    float* part = (float*)d_ws;                // 2112 floats of scratch
    float* out  = (float*)d_out;
    depth_loss_part<<<NBLK_, 256, 0, stream>>>(gt, dp, part);
    depth_loss_final<<<1, 256, 0, stream>>>(part, out);
}